// Round 1
// 818.350 us; speedup vs baseline: 1.1202x; 1.1202x over previous
//
#include <hip/hip_runtime.h>
#include <hip/hip_bf16.h>
#include <hip/hip_fp16.h>

#define H 2048
#define E 8
#define DFF 8192
#define NTOK 4096
#define NB 4  // H/512 scale blocks

typedef _Float16 f16x8 __attribute__((ext_vector_type(8)));
typedef float f32x4 __attribute__((ext_vector_type(4)));

#define AS1 __attribute__((address_space(1)))
#define AS3 __attribute__((address_space(3)))

__device__ __forceinline__ void gl_lds16(const void* g, void* l) {
    __builtin_amdgcn_global_load_lds((const AS1 unsigned int*)g,
                                     (AS3 unsigned int*)l, 16, 0, 0);
}

__device__ __forceinline__ float gelu_f(float x) {
    float u = 0.7978845608028654f * x * (1.0f + 0.044715f * x * x);
    float t = fabsf(u);
    float e = __expf(-2.0f * t);
    float th = (1.0f - e) / (1.0f + e);
    th = copysignf(th, u);
    return 0.5f * x * (1.0f + th);
}

// ---------------- router (fp32) + x -> fp16 cast ----------------
__global__ __launch_bounds__(256) void router_cast_kernel(
    const float* __restrict__ x, const float* __restrict__ rw,
    float* __restrict__ probs, _Float16* __restrict__ xh)
{
    int n = blockIdx.x, t = threadIdx.x;
    float acc[E];
#pragma unroll
    for (int e = 0; e < E; ++e) acc[e] = 0.f;
    const float* xr = x + (size_t)n * H;
#pragma unroll
    for (int k = 0; k < H / 256; ++k) {
        int h = t + k * 256;
        float xv = xr[h];
        xh[(size_t)n * H + h] = (_Float16)xv;
        const float4* r4 = reinterpret_cast<const float4*>(rw + (size_t)h * E);
        float4 a = r4[0], b = r4[1];
        acc[0] += xv * a.x; acc[1] += xv * a.y; acc[2] += xv * a.z; acc[3] += xv * a.w;
        acc[4] += xv * b.x; acc[5] += xv * b.y; acc[6] += xv * b.z; acc[7] += xv * b.w;
    }
#pragma unroll
    for (int e = 0; e < E; ++e) {
        float v = acc[e];
#pragma unroll
        for (int o = 32; o > 0; o >>= 1) v += __shfl_down(v, o, 64);
        acc[e] = v;
    }
    __shared__ float red[4][E];
    int wave = t >> 6, lane = t & 63;
    if (lane == 0) {
#pragma unroll
        for (int e = 0; e < E; ++e) red[wave][e] = acc[e];
    }
    __syncthreads();
    if (t == 0) {
        float lg[E];
        float mx = -1e30f;
#pragma unroll
        for (int e = 0; e < E; ++e) {
            lg[e] = red[0][e] + red[1][e] + red[2][e] + red[3][e];
            mx = fmaxf(mx, lg[e]);
        }
        float s = 0.f;
#pragma unroll
        for (int e = 0; e < E; ++e) { lg[e] = expf(lg[e] - mx); s += lg[e]; }
        float inv = 1.f / s;
#pragma unroll
        for (int e = 0; e < E; ++e) {
            float p = lg[e] * inv;
            p = __half2float(__float2half(p));
            probs[(size_t)n * E + e] = p;
        }
    }
}

// ---------------- transpose + cast fp32 [R,C] -> fp16 [C,R] ----------------
__global__ __launch_bounds__(256) void transpose_cast_kernel(
    const float* __restrict__ src, _Float16* __restrict__ dst, int R, int C)
{
    __shared__ float tile[32][33];
    int tx = threadIdx.x & 31, ty = threadIdx.x >> 5;
    int c0 = blockIdx.x * 32, r0 = blockIdx.y * 32;
#pragma unroll
    for (int i = ty; i < 32; i += 8)
        tile[i][tx] = src[(size_t)(r0 + i) * C + c0 + tx];
    __syncthreads();
#pragma unroll
    for (int i = ty; i < 32; i += 8)
        dst[(size_t)(c0 + i) * R + r0 + tx] = (_Float16)tile[tx][i];
}

// ---------------- NF4 dequant + expert mix -> moe (fp32) ----------------
__global__ __launch_bounds__(256) void moe_kernel(
    const int* __restrict__ nf4, const float* __restrict__ mean,
    const float* __restrict__ stdv, const float* __restrict__ cb,
    const float* __restrict__ probs, float* __restrict__ moe)
{
    int n = blockIdx.x, t = threadIdx.x;
    __shared__ float cbl[32];
    __shared__ float ps[E][NB];
    __shared__ float cmean[NB];
    if (t < 16) { float v = cb[t]; cbl[t] = v; cbl[t + 16] = v; }
    else if (t >= 32 && t < 64) {
        int e = (t - 32) >> 2, b = t & 3;
        ps[e][b] = probs[(size_t)n * E + e] * stdv[((size_t)n * E + e) * NB + b];
    } else if (t >= 64 && t < 68) {
        int b = t - 64; float s = 0.f;
        for (int e = 0; e < E; ++e)
            s += probs[(size_t)n * E + e] * mean[((size_t)n * E + e) * NB + b];
        cmean[b] = s;
    }
    __syncthreads();
    int cboff = (t & 1) << 4;
    const int* w = nf4 + (size_t)n * (E * H / 2);
    float2* outp = reinterpret_cast<float2*>(moe + (size_t)n * H);
#pragma unroll
    for (int k = 0; k < 4; ++k) {
        int j = t + k * 256;
        float psr[E];
#pragma unroll
        for (int e = 0; e < E; ++e) psr[e] = ps[e][k];
        float cm = cmean[k];
        float aL = cm, aH = cm;
#pragma unroll
        for (int e = 0; e < E; ++e) {
            int word = w[e * (H / 2) + j];
            aL += psr[e] * cbl[(word & 15) + cboff];
            aH += psr[e] * cbl[((word >> 4) & 15) + cboff];
        }
        outp[j] = make_float2(aL, aH);
    }
}

// ---------------- fp16 MFMA GEMM, 256-wide tile, 4-phase counted-vmcnt ----
// C = A[M,K] * Bt[N,K]^T.  512 threads / 8 waves, BK=64, double-buffered LDS
// (2 x (BM+BN)*BK*2 bytes), k-seg-major LDS layout (bank-conflict-free, the
// staging permutation is done via per-lane GLOBAL addresses so global_load_lds
// can write linearly).  Per K-tile, 4 phases:
//   p0: issue 2 stage loads; vmcnt(2) (prior tile fully landed, 2 newest in
//       flight); barrier; ds_read A-half0 + B-half0; MFMA quad(0,0); barrier
//   p1: issue 2 stage loads; ds_read B-half1; MFMA quad(0,1); barrier
//   p2: issue 2 stage loads; ds_read A-half1; MFMA quad(1,1); barrier
//   p3: [issue 2 stage loads]; MFMA quad(1,0) (B-half0 regs still live);
//       lgkmcnt(0); barrier
// vmcnt never drains to 0 in the main loop (T3+T4); MFMA clusters wrapped in
// s_setprio (T5).  BN=256: waves 2Mx4N, per-wave 128x64 (acc 8x4).
// BN=128: waves 4Mx2N, per-wave 64x64 (acc 4x4), grid stays >= 1 block/CU.
// EPI 0: out = f16(gelu(acc));  EPI 1: out = acc + addsrc (float).
template <int EPI, int BN, typename OT>
__global__ __launch_bounds__(512, 2) void gemm256_kernel(
    const _Float16* __restrict__ A, const _Float16* __restrict__ Bt,
    const float* __restrict__ addsrc, OT* __restrict__ outb,
    int K, int N, int bwShift)
{
    constexpr int BM = 256;
    constexpr int BK = 64;
    constexpr unsigned ASZ = BM * BK * 2;      // 32 KB
    constexpr unsigned BSZ = BN * BK * 2;      // 32 or 16 KB
    constexpr unsigned BUFSZ = ASZ + BSZ;
    constexpr int NLB = BSZ / 8192;            // B stage instrs: 4 or 2
    constexpr int FI = (BN == 256) ? 8 : 4;    // A frags per wave (16-row units)
    constexpr int FIH = FI / 2;
    constexpr int SBS = (BN == 256) ? 16 : 32; // halves per B stage instr step

    __shared__ uint4 lds_u4[2 * BUFSZ / 16];
    char* lds = (char*)lds_u4;

    int t = threadIdx.x;
    int id = blockIdx.x;
    int xcd = id & 7, chunk = id >> 3;
    int bx = (xcd << bwShift) | (chunk & ((1 << bwShift) - 1));
    int by = chunk >> bwShift;
    int m0 = by * BM, n0 = bx * BN;

    // staging source pointers (units: halves). LDS chunk (s*512+t) maps to
    // (kseg = chunk/ROWS, row = chunk%ROWS); source addr reproduces that.
    const unsigned short* sA = (const unsigned short*)A
        + (size_t)(m0 + (t & (BM - 1))) * K + (t >> 8) * 8;
    const unsigned short* sB = (const unsigned short*)Bt
        + (size_t)(n0 + (t & (BN - 1))) * K + (t >> ((BN == 256) ? 8 : 7)) * 8;
    unsigned dstT = (unsigned)t * 16;

    int lane = t & 63, wave = t >> 6;
    int wr, wc;
    if constexpr (BN == 256) { wr = wave >> 2; wc = wave & 3; }
    else                     { wr = wave >> 1; wc = wave & 1; }
    int mb = wr * (FI * 16);
    int nb = wc * 64;
    int q = lane >> 4, m16 = lane & 15;

    f32x4 acc[FI][4] = {};
    f16x8 af[FI];       // one A half: FIH i-frags x 2 kh
    f16x8 bh[2][4];     // two B halves, each: 2 j-frags x 2 kh

    // prologue: stage tile 0 into buffer 0
#pragma unroll
    for (int s = 0; s < 4; ++s)
        gl_lds16(sA + s * 16, lds + s * 8192 + dstT);
#pragma unroll
    for (int s = 0; s < NLB; ++s)
        gl_lds16(sB + s * SBS, lds + ASZ + s * 8192 + dstT);

    unsigned cur = 0;
    for (int k0 = 0; k0 < K; k0 += BK) {
        unsigned nxt = cur ^ BUFSZ;
        char* ldsR = lds + cur;
        char* ldsW = lds + nxt;
        bool more = (k0 + BK < K);
        int kn = k0 + BK;

        // ---------------- phase 0 ----------------
        if (more) {
            gl_lds16(sA + kn,      ldsW + dstT);
            gl_lds16(sA + kn + 16, ldsW + 8192 + dstT);
            asm volatile("s_waitcnt vmcnt(2)" ::: "memory");
        } else {
            asm volatile("s_waitcnt vmcnt(0)" ::: "memory");
        }
        asm volatile("s_barrier" ::: "memory");
#pragma unroll
        for (int il = 0; il < FIH; ++il)
#pragma unroll
            for (int kh = 0; kh < 2; ++kh)
                af[il * 2 + kh] = *(const f16x8*)(ldsR +
                    (unsigned)((kh * 4 + q) * BM + mb + il * 16 + m16) * 16u);
#pragma unroll
        for (int jl = 0; jl < 2; ++jl)
#pragma unroll
            for (int kh = 0; kh < 2; ++kh)
                bh[0][jl * 2 + kh] = *(const f16x8*)(ldsR + ASZ +
                    (unsigned)((kh * 4 + q) * BN + nb + jl * 16 + m16) * 16u);
        __builtin_amdgcn_s_setprio(1);
#pragma unroll
        for (int il = 0; il < FIH; ++il)
#pragma unroll
            for (int jl = 0; jl < 2; ++jl)
#pragma unroll
                for (int kh = 0; kh < 2; ++kh)
                    acc[il][jl] = __builtin_amdgcn_mfma_f32_16x16x32_f16(
                        af[il * 2 + kh], bh[0][jl * 2 + kh], acc[il][jl], 0, 0, 0);
        __builtin_amdgcn_s_setprio(0);
        asm volatile("s_barrier" ::: "memory");

        // ---------------- phase 1 ----------------
        if (more) {
            gl_lds16(sA + kn + 32, ldsW + 2 * 8192 + dstT);
            gl_lds16(sA + kn + 48, ldsW + 3 * 8192 + dstT);
        }
#pragma unroll
        for (int jl = 0; jl < 2; ++jl)
#pragma unroll
            for (int kh = 0; kh < 2; ++kh)
                bh[1][jl * 2 + kh] = *(const f16x8*)(ldsR + ASZ +
                    (unsigned)((kh * 4 + q) * BN + nb + (2 + jl) * 16 + m16) * 16u);
        __builtin_amdgcn_s_setprio(1);
#pragma unroll
        for (int il = 0; il < FIH; ++il)
#pragma unroll
            for (int jl = 0; jl < 2; ++jl)
#pragma unroll
                for (int kh = 0; kh < 2; ++kh)
                    acc[il][2 + jl] = __builtin_amdgcn_mfma_f32_16x16x32_f16(
                        af[il * 2 + kh], bh[1][jl * 2 + kh], acc[il][2 + jl], 0, 0, 0);
        __builtin_amdgcn_s_setprio(0);
        asm volatile("s_barrier" ::: "memory");

        // ---------------- phase 2 ----------------
        if (more) {
            gl_lds16(sB + kn,       ldsW + ASZ + dstT);
            gl_lds16(sB + kn + SBS, ldsW + ASZ + 8192 + dstT);
        }
#pragma unroll
        for (int il = 0; il < FIH; ++il)
#pragma unroll
            for (int kh = 0; kh < 2; ++kh)
                af[il * 2 + kh] = *(const f16x8*)(ldsR +
                    (unsigned)((kh * 4 + q) * BM + mb + (FIH + il) * 16 + m16) * 16u);
        __builtin_amdgcn_s_setprio(1);
#pragma unroll
        for (int il = 0; il < FIH; ++il)
#pragma unroll
            for (int jl = 0; jl < 2; ++jl)
#pragma unroll
                for (int kh = 0; kh < 2; ++kh)
                    acc[FIH + il][2 + jl] = __builtin_amdgcn_mfma_f32_16x16x32_f16(
                        af[il * 2 + kh], bh[1][jl * 2 + kh], acc[FIH + il][2 + jl], 0, 0, 0);
        __builtin_amdgcn_s_setprio(0);
        asm volatile("s_barrier" ::: "memory");

        // ---------------- phase 3 ----------------
        if constexpr (NLB == 4) {
            if (more) {
                gl_lds16(sB + kn + 2 * SBS, ldsW + ASZ + 2 * 8192 + dstT);
                gl_lds16(sB + kn + 3 * SBS, ldsW + ASZ + 3 * 8192 + dstT);
            }
        }
        __builtin_amdgcn_s_setprio(1);
#pragma unroll
        for (int il = 0; il < FIH; ++il)
#pragma unroll
            for (int jl = 0; jl < 2; ++jl)
#pragma unroll
                for (int kh = 0; kh < 2; ++kh)
                    acc[FIH + il][jl] = __builtin_amdgcn_mfma_f32_16x16x32_f16(
                        af[il * 2 + kh], bh[0][jl * 2 + kh], acc[FIH + il][jl], 0, 0, 0);
        __builtin_amdgcn_s_setprio(0);
        asm volatile("s_waitcnt lgkmcnt(0)" ::: "memory");
        asm volatile("s_barrier" ::: "memory");
        cur = nxt;
    }

    // epilogue (same verified C/D mapping as before)
#pragma unroll
    for (int i = 0; i < FI; ++i)
#pragma unroll
        for (int j = 0; j < 4; ++j) {
            int row = m0 + mb + i * 16 + q * 4;
            int col = n0 + nb + j * 16 + m16;
#pragma unroll
            for (int rix = 0; rix < 4; ++rix) {
                float v = acc[i][j][rix];
                size_t o = (size_t)(row + rix) * N + col;
                if constexpr (EPI == 0) {
                    outb[o] = (OT)gelu_f(v);
                } else {
                    outb[o] = (OT)(v + addsrc[o]);
                }
            }
        }
}

extern "C" void kernel_launch(void* const* d_in, const int* in_sizes, int n_in,
                              void* d_out, int out_size, void* d_ws, size_t ws_size,
                              hipStream_t stream) {
    const float* x    = (const float*)d_in[0];
    const float* rw   = (const float*)d_in[1];
    const int*   nf4  = (const int*)d_in[2];
    const float* mean = (const float*)d_in[3];
    const float* stdv = (const float*)d_in[4];
    const float* cb   = (const float*)d_in[5];
    const float* w1   = (const float*)d_in[6];
    const float* w2   = (const float*)d_in[7];
    float* out = (float*)d_out;

    char* ws = (char*)d_ws;
    float* probs      = (float*)ws;                          // 128 KB
    float* moe        = (float*)(ws + 131072);               // 32 MB
    _Float16* xh      = (_Float16*)(ws + 33685504);          // 16 MB  [NTOK,H]
    _Float16* w1t     = (_Float16*)(ws + 50462720);          // 32 MB  [DFF,H]
    _Float16* w2t     = (_Float16*)(ws + 84017152);          // 32 MB  [H,DFF]
    _Float16* hid     = (_Float16*)(ws + 117571584);         // 64 MB  [NTOK,DFF]

    router_cast_kernel<<<NTOK, 256, 0, stream>>>(x, rw, probs, xh);
    transpose_cast_kernel<<<dim3(DFF / 32, H / 32), 256, 0, stream>>>(w1, w1t, H, DFF);
    transpose_cast_kernel<<<dim3(H / 32, DFF / 32), 256, 0, stream>>>(w2, w2t, DFF, H);
    moe_kernel<<<NTOK, 256, 0, stream>>>(nf4, mean, stdv, cb, probs, moe);
    // hidden = gelu(x @ w1): 256x256 tiles, grid 16x32 -> 512 blocks (bwShift=2)
    gemm256_kernel<0, 256, _Float16><<<512, 512, 0, stream>>>(xh, w1t, nullptr, hid, H, DFF, 2);
    // out = moe + hidden @ w2: 256x128 tiles, grid 16x16 -> 256 blocks (bwShift=1)
    gemm256_kernel<1, 128, float><<<256, 512, 0, stream>>>(hid, w2t, moe, out, DFF, H, 1);
}